// Round 3
// baseline (2621.783 us; speedup 1.0000x reference)
//
#include <hip/hip_runtime.h>
#include <math.h>

// ---------------------------------------------------------------------------
// MoE transformer block (2 hops) + RMSNorm + tied-embedding logits.
// bf16 hi/lo split MFMA GEMMs (A*B ~= Ah*Bh + Al*Bh + Ah*Bl), fp32 everywhere
// that affects routing decisions. m97-style 128x128xBK32 GEMM,
// mfma_f32_16x16x32_bf16, A=[M][K] hi/lo bf16, B=[N][K] hi/lo bf16 (weights
// pre-transposed+split once per launch when workspace allows).
// RoPE tables computed in double with fr rounded to fp32 (mimics JAX).
// ---------------------------------------------------------------------------

#define Tn   2048
#define Dmod 1024
#define Vn   32000
#define En   16
#define CAPn 512
#define DHn  64
#define DFFn 4096
#define HOPSn 2

typedef unsigned short u16;
typedef short s8v __attribute__((ext_vector_type(8)));
typedef float f4v __attribute__((ext_vector_type(4)));

#define MFMA_BF16(a, b, c) __builtin_amdgcn_mfma_f32_16x16x32_bf16((a), (b), (c), 0, 0, 0)

#if __has_builtin(__builtin_amdgcn_global_load_lds)
#define GLOAD16(g, l)                                              \
  __builtin_amdgcn_global_load_lds(                                \
      (const __attribute__((address_space(1))) void*)(g),          \
      (__attribute__((address_space(3))) void*)(l), 16, 0, 0)
#else
#define GLOAD16(g, l) (*(uint4*)(l) = *(const uint4*)(g))
#endif

__device__ __forceinline__ float gelu_tanh(float x) {
  float c = 0.7978845608028654f * (x + 0.044715f * x * x * x);
  return 0.5f * x * (1.0f + tanhf(c));
}

__device__ __forceinline__ u16 bf16_rne(float x) {
  unsigned u = __float_as_uint(x);
  return (u16)((u + 0x7fffu + ((u >> 16) & 1u)) >> 16);
}
__device__ __forceinline__ float bf16_to_f(u16 h) {
  return __uint_as_float(((unsigned)h) << 16);
}
__device__ __forceinline__ void split2(float x, u16& hi, u16& lo) {
  hi = bf16_rne(x);
  lo = bf16_rne(x - bf16_to_f(hi));  // exact subtraction (Sterbenz)
}
// split a float4 into hi/lo bf16 quads and store as 8B each
__device__ __forceinline__ void split_store4(float4 v, u16* ph, u16* pl) {
  u16 h0, h1, h2, h3, l0, l1, l2, l3;
  split2(v.x, h0, l0); split2(v.y, h1, l1);
  split2(v.z, h2, l2); split2(v.w, h3, l3);
  uint2 hw = make_uint2((unsigned)h0 | ((unsigned)h1 << 16),
                        (unsigned)h2 | ((unsigned)h3 << 16));
  uint2 lw = make_uint2((unsigned)l0 | ((unsigned)l1 << 16),
                        (unsigned)l2 | ((unsigned)l3 << 16));
  *(uint2*)ph = hw;
  *(uint2*)pl = lw;
}

// ---------------- RoPE tables (double precision, JAX-matching rounding) ----
__global__ __launch_bounds__(256) void rope_tables(float* __restrict__ cosT,
                                                   float* __restrict__ sinT) {
  int i = blockIdx.x * 256 + threadIdx.x;
  if (i >= Tn * DHn) return;
  int t = i / DHn, j = i % DHn;
  // inv as correctly-rounded fp32 of 10000^(-2(j&31)/64)
  float inv32 = (float)pow(10000.0, -(double)(2 * (j & 31)) / 64.0);
  // fr rounded to fp32 exactly like JAX (t * inv in fp32)
  float fr32 = (float)t * inv32;
  cosT[i] = (float)cos((double)fr32);
  sinT[i] = (float)sin((double)fr32);
}

// ---------------- Embedding gather ----------------
__global__ __launch_bounds__(256) void embed_gather(const int* __restrict__ ids,
                                                    const float* __restrict__ ew,
                                                    float* __restrict__ h) {
  int i = blockIdx.x * 256 + threadIdx.x;  // over T*D/4
  if (i >= Tn * Dmod / 4) return;
  int t = i / (Dmod / 4);
  int d4 = i % (Dmod / 4);
  float4 v = *(const float4*)(ew + (long)ids[t] * Dmod + d4 * 4);
  *(float4*)(h + (long)t * Dmod + d4 * 4) = v;
}

// ---------------- Router: logits + softmax + top2 (1 wave per token) -------
__global__ __launch_bounds__(64) void router_kernel(
    const float* __restrict__ h, const float* __restrict__ wr,
    float* __restrict__ logits, float* __restrict__ probs,
    int* __restrict__ tope, int* __restrict__ slotmap) {
  int t = blockIdx.x;
  int lane = threadIdx.x;
  int e = lane & 15, chunk = lane >> 4;
  const float* hr = h + (long)t * Dmod;
  float acc = 0.f;
  int dbeg = chunk * 256;
  for (int d = dbeg; d < dbeg + 256; ++d)
    acc = fmaf(hr[d], wr[d * En + e], acc);
  acc += __shfl_xor(acc, 16);
  acc += __shfl_xor(acc, 32);
  float lg = acc;  // every lane now holds logit for expert (lane&15)
  float mx = lg;
  mx = fmaxf(mx, __shfl_xor(mx, 1));
  mx = fmaxf(mx, __shfl_xor(mx, 2));
  mx = fmaxf(mx, __shfl_xor(mx, 4));
  mx = fmaxf(mx, __shfl_xor(mx, 8));
  float ex = expf(lg - mx);
  float sm = ex;
  sm += __shfl_xor(sm, 1);
  sm += __shfl_xor(sm, 2);
  sm += __shfl_xor(sm, 4);
  sm += __shfl_xor(sm, 8);
  float pr = ex / sm;
  if (lane < 16) {
    logits[t * En + e] = lg;
    probs[t * En + e] = pr;
    slotmap[t * En + e] = -1;
  }
  // serial top-2, tie -> lower index (matches jax.lax.top_k)
  float best = -1e30f, sec = -1e30f;
  int be = 0, se = 0;
  for (int q = 0; q < 16; ++q) {
    float v = __shfl(lg, q);
    if (v > best) { sec = best; se = be; best = v; be = q; }
    else if (v > sec) { sec = v; se = q; }
  }
  if (lane == 0) { tope[2 * t] = be; tope[2 * t + 1] = se; }
}

// ---------------- Capacity select + stable order (1 block per expert) ------
__global__ __launch_bounds__(256) void assign_kernel(
    const float* __restrict__ logits, const int* __restrict__ tope,
    int* __restrict__ etok, int* __restrict__ slotmap) {
  __shared__ int cand_t[Tn];
  __shared__ float cand_v[Tn];
  __shared__ unsigned char keptf[Tn];
  __shared__ int cnt;
  int e = blockIdx.x;
  if (threadIdx.x == 0) cnt = 0;
  __syncthreads();
  for (int t = threadIdx.x; t < Tn; t += 256) {
    if (tope[2 * t] == e || tope[2 * t + 1] == e) {
      int idx = atomicAdd(&cnt, 1);
      cand_t[idx] = t;
      cand_v[idx] = logits[t * En + e];
    }
  }
  __syncthreads();
  int n = cnt;
  for (int i = threadIdx.x; i < n; i += 256) {
    bool kept = true;
    if (n > CAPn) {
      // rank by (value desc, token index asc) — matches top_k tie-breaking
      int rank = 0;
      float vi = cand_v[i];
      int ti = cand_t[i];
      for (int j = 0; j < n; ++j) {
        float vj = cand_v[j];
        if (vj > vi || (vj == vi && cand_t[j] < ti)) ++rank;
      }
      kept = rank < CAPn;
    }
    keptf[i] = kept ? 1 : 0;
  }
  __syncthreads();
  for (int i = threadIdx.x; i < n; i += 256) {
    if (keptf[i]) {
      int ti = cand_t[i];
      int pos = 0;
      for (int j = 0; j < n; ++j)
        pos += (keptf[j] && cand_t[j] < ti) ? 1 : 0;
      etok[e * CAPn + pos] = ti;
      slotmap[ti * En + e] = pos;
    }
  }
  __syncthreads();
  int nk = n < CAPn ? n : CAPn;
  for (int c = nk + threadIdx.x; c < CAPn; c += 256)
    etok[e * CAPn + c] = -1;
}

// ---------------- Dispatch gather + RoPE -> split bf16 (1 block/slot) ------
__global__ __launch_bounds__(256) void dispatch_rope(
    const int* __restrict__ etok, const float* __restrict__ h,
    const float* __restrict__ cosT, const float* __restrict__ sinT,
    u16* __restrict__ xh, u16* __restrict__ xl) {
  int ec = blockIdx.x;  // e*CAP + c
  int t = etok[ec];
  int d0 = threadIdx.x * 4;
  u16* oh = xh + (long)ec * Dmod + d0;
  u16* ol = xl + (long)ec * Dmod + d0;
  if (t < 0) {
    *(uint2*)oh = make_uint2(0u, 0u);
    *(uint2*)ol = make_uint2(0u, 0u);
    return;
  }
  const float* hr = h + (long)t * Dmod;
  float4 x = *(const float4*)(hr + d0);
  int j0 = d0 & 63;  // position within head (whole float4 in same half)
  float4 c4 = *(const float4*)(cosT + (long)t * DHn + j0);
  float4 s4 = *(const float4*)(sinT + (long)t * DHn + j0);
  bool lo = j0 < 32;
  float4 xo = lo ? *(const float4*)(hr + d0 + 32)
                 : *(const float4*)(hr + d0 - 32);
  float sg = lo ? -1.f : 1.f;
  float4 r;
  r.x = x.x * c4.x + sg * xo.x * s4.x;
  r.y = x.y * c4.y + sg * xo.y * s4.y;
  r.z = x.z * c4.z + sg * xo.z * s4.z;
  r.w = x.w * c4.w + sg * xo.w * s4.w;
  split_store4(r, oh, ol);
}

// ---------------- Weight transpose + split: fp32 [K][N] -> bf16 [N][K] x2 --
__global__ __launch_bounds__(256) void transpose_split(
    const float* __restrict__ W, u16* __restrict__ Th, u16* __restrict__ Tl,
    int K, int N) {
  __shared__ float tbuf[64][65];
  long z = blockIdx.z;
  W += z * (long)K * N;
  Th += z * (long)K * N;
  Tl += z * (long)K * N;
  int k0 = blockIdx.y * 64, n0 = blockIdx.x * 64;
  int tid = threadIdx.x;
#pragma unroll
  for (int p = 0; p < 4; ++p) {  // load 64x64 fp32 tile, coalesced
    int kr = p * 16 + (tid >> 4);
    int nc = (tid & 15) * 4;
    float4 v = *(const float4*)&W[(long)(k0 + kr) * N + n0 + nc];
    tbuf[kr][nc] = v.x; tbuf[kr][nc + 1] = v.y;
    tbuf[kr][nc + 2] = v.z; tbuf[kr][nc + 3] = v.w;
  }
  __syncthreads();
  int n = tid >> 2;
  int kc = (tid & 3) * 16;
  u16* th = &Th[(long)(n0 + n) * K + k0 + kc];
  u16* tl = &Tl[(long)(n0 + n) * K + k0 + kc];
#pragma unroll
  for (int j = 0; j < 4; ++j) {
    float4 v = make_float4(tbuf[kc + 4 * j][n], tbuf[kc + 4 * j + 1][n],
                           tbuf[kc + 4 * j + 2][n], tbuf[kc + 4 * j + 3][n]);
    split_store4(v, th + 4 * j, tl + 4 * j);
  }
}

// ---------------- bf16x3 split MFMA GEMM, 128x128 tile, BK=32 --------------
// A: [M][K] bf16 hi/lo. B: [N][K] bf16 hi/lo (or fp32 [N][K] if B_FP32,
// converted during staging). C: fp32 [M][N], or split bf16 pair if OUT_SPLIT
// (with GELU applied first if GELU_OUT).
template <bool B_FP32, bool GELU_OUT, bool OUT_SPLIT>
__global__ __launch_bounds__(256) void gemm_mfma(
    const u16* __restrict__ Ah, const u16* __restrict__ Al,
    const u16* __restrict__ Bh, const u16* __restrict__ Bl,
    const float* __restrict__ Bf, float* __restrict__ Cf,
    u16* __restrict__ Ch, u16* __restrict__ Cl, int M, int N, int K,
    long sAz, long sBz, long sCz) {
  __shared__ u16 smem[4][128][32];  // [Ah,Al,Bh,Bl][row][k] 32 KiB
  long z = blockIdx.z;
  Ah += z * sAz; Al += z * sAz;
  if constexpr (B_FP32) { Bf += z * sBz; }
  else { Bh += z * sBz; Bl += z * sBz; }
  if constexpr (OUT_SPLIT) { Ch += z * sCz; Cl += z * sCz; }
  else { Cf += z * sCz; }

  int bm = blockIdx.y * 128, bn = blockIdx.x * 128;
  int tid = threadIdx.x;
  int lane = tid & 63;
  int wid = tid >> 6;
  int wr = wid >> 1, wc = wid & 1;   // wave quadrant (2x2 of 64x64)
  int r16 = lane & 15, kg = lane >> 4;

  f4v acc[4][4] = {};

  // staging geometry: per global_load_lds call, wave w covers 16 rows;
  // lane i lands at LDS base + i*16B which equals row (wid*16 + i>>2),
  // k-offset (i&3)*8 — matching its per-lane global address.
  int srow = (wid << 4) + (lane >> 2);  // 0..63
  int sk8 = (lane & 3) * 8;             // ushort offset (16B granule)

  for (int k0 = 0; k0 < K; k0 += 32) {
    {
      long ao = (long)(bm + srow) * K + k0 + sk8;
      GLOAD16(Ah + ao, &smem[0][srow][sk8]);
      GLOAD16(Ah + ao + 64 * (long)K, &smem[0][srow + 64][sk8]);
      GLOAD16(Al + ao, &smem[1][srow][sk8]);
      GLOAD16(Al + ao + 64 * (long)K, &smem[1][srow + 64][sk8]);
    }
    if constexpr (!B_FP32) {
      long bo = (long)(bn + srow) * K + k0 + sk8;
      GLOAD16(Bh + bo, &smem[2][srow][sk8]);
      GLOAD16(Bh + bo + 64 * (long)K, &smem[2][srow + 64][sk8]);
      GLOAD16(Bl + bo, &smem[3][srow][sk8]);
      GLOAD16(Bl + bo + 64 * (long)K, &smem[3][srow + 64][sk8]);
    } else {
      // fp32 B [N][K]: read float4, convert to hi/lo, ds_write 8B each
#pragma unroll
      for (int p = 0; p < 4; ++p) {
        int n = p * 32 + (tid >> 3);
        int kc = (tid & 7) * 4;
        float4 v = *(const float4*)&Bf[(long)(bn + n) * K + k0 + kc];
        split_store4(v, &smem[2][n][kc], &smem[3][n][kc]);
      }
    }
    __syncthreads();
    s8v ah[4], al[4], bh[4], bl[4];
#pragma unroll
    for (int i = 0; i < 4; ++i) {
      ah[i] = *(const s8v*)&smem[0][wr * 64 + i * 16 + r16][kg * 8];
      al[i] = *(const s8v*)&smem[1][wr * 64 + i * 16 + r16][kg * 8];
      bh[i] = *(const s8v*)&smem[2][wc * 64 + i * 16 + r16][kg * 8];
      bl[i] = *(const s8v*)&smem[3][wc * 64 + i * 16 + r16][kg * 8];
    }
#pragma unroll
    for (int i = 0; i < 4; ++i)
#pragma unroll
      for (int j = 0; j < 4; ++j) {
        acc[i][j] = MFMA_BF16(ah[i], bh[j], acc[i][j]);
        acc[i][j] = MFMA_BF16(al[i], bh[j], acc[i][j]);
        acc[i][j] = MFMA_BF16(ah[i], bl[j], acc[i][j]);
      }
    __syncthreads();
  }

  // epilogue: C/D frag mapping col=lane&15, row=(lane>>4)*4+reg (m89)
#pragma unroll
  for (int i = 0; i < 4; ++i)
#pragma unroll
    for (int q = 0; q < 4; ++q) {
      int row = bm + wr * 64 + i * 16 + kg * 4 + q;
#pragma unroll
      for (int j = 0; j < 4; ++j) {
        int col = bn + wc * 64 + j * 16 + r16;
        float v = acc[i][j][q];
        if constexpr (GELU_OUT) v = gelu_tanh(v);
        if constexpr (OUT_SPLIT) {
          u16 h, l;
          split2(v, h, l);
          Ch[(long)row * N + col] = h;
          Cl[(long)row * N + col] = l;
        } else {
          Cf[(long)row * N + col] = v;
        }
      }
    }
}

// ---------------- Combine + residual (1 block per token) ----------------
__global__ __launch_bounds__(256) void combine_kernel(
    const float* __restrict__ h, const float* __restrict__ eout,
    const float* __restrict__ probs, const int* __restrict__ tope,
    const int* __restrict__ slotmap, float* __restrict__ hout) {
  int t = blockIdx.x;
  int e0 = tope[2 * t], e1 = tope[2 * t + 1];
  int s0 = slotmap[t * En + e0], s1 = slotmap[t * En + e1];
  float w0 = (s0 >= 0) ? probs[t * En + e0] : 0.f;
  float w1 = (s1 >= 0) ? probs[t * En + e1] : 0.f;
  float rho = w0 + w1;
  int d0 = threadIdx.x * 4;
  float4 hv = *(const float4*)(h + (long)t * Dmod + d0);
  float cx = 0.f, cy = 0.f, cz = 0.f, cw = 0.f;
  if (s0 >= 0) {
    float4 v = *(const float4*)(eout + ((long)e0 * CAPn + s0) * Dmod + d0);
    cx += w0 * v.x; cy += w0 * v.y; cz += w0 * v.z; cw += w0 * v.w;
  }
  if (s1 >= 0) {
    float4 v = *(const float4*)(eout + ((long)e1 * CAPn + s1) * Dmod + d0);
    cx += w1 * v.x; cy += w1 * v.y; cz += w1 * v.z; cw += w1 * v.w;
  }
  float4 r;
  r.x = (hv.x + cx) - rho * hv.x;
  r.y = (hv.y + cy) - rho * hv.y;
  r.z = (hv.z + cz) - rho * hv.z;
  r.w = (hv.w + cw) - rho * hv.w;
  *(float4*)(hout + (long)t * Dmod + d0) = r;
}

// ---------------- RMSNorm -> split bf16 (1 block per token) ----------------
__global__ __launch_bounds__(256) void rmsnorm_kernel(
    const float* __restrict__ h, const float* __restrict__ g,
    u16* __restrict__ oh, u16* __restrict__ ol) {
  int t = blockIdx.x;
  int d0 = threadIdx.x * 4;
  float4 x = *(const float4*)(h + (long)t * Dmod + d0);
  float ss = x.x * x.x + x.y * x.y + x.z * x.z + x.w * x.w;
  ss += __shfl_xor(ss, 1);  ss += __shfl_xor(ss, 2);
  ss += __shfl_xor(ss, 4);  ss += __shfl_xor(ss, 8);
  ss += __shfl_xor(ss, 16); ss += __shfl_xor(ss, 32);
  __shared__ float wsum[4];
  if ((threadIdx.x & 63) == 0) wsum[threadIdx.x >> 6] = ss;
  __syncthreads();
  float total = wsum[0] + wsum[1] + wsum[2] + wsum[3];
  float inv = 1.0f / sqrtf(total / (float)Dmod + 1e-6f);
  float4 gv = *(const float4*)(g + d0);
  float4 r;
  r.x = x.x * gv.x * inv; r.y = x.y * gv.y * inv;
  r.z = x.z * gv.z * inv; r.w = x.w * gv.w * inv;
  split_store4(r, oh + (long)t * Dmod + d0, ol + (long)t * Dmod + d0);
}

// ---------------------------------------------------------------------------
extern "C" void kernel_launch(void* const* d_in, const int* in_sizes, int n_in,
                              void* d_out, int out_size, void* d_ws,
                              size_t ws_size, hipStream_t stream) {
  const int* ids = (const int*)d_in[0];
  const float* ew = (const float*)d_in[1];
  const float* rw = (const float*)d_in[2];
  const float* w1 = (const float*)d_in[3];
  const float* w2 = (const float*)d_in[4];
  const float* lns = (const float*)d_in[5];
  float* out = (float*)d_out;

  char* p = (char*)d_ws;
  auto alloc = [&](size_t bytes) -> void* {
    void* r = (void*)p;
    p += (bytes + 255) & ~(size_t)255;
    return r;
  };
  float* h = (float*)alloc((size_t)Tn * Dmod * 4);
  float* h2 = (float*)alloc((size_t)Tn * Dmod * 4);
  float* cosT = (float*)alloc((size_t)Tn * DHn * 4);
  float* sinT = (float*)alloc((size_t)Tn * DHn * 4);
  float* logits = (float*)alloc((size_t)Tn * En * 4);
  float* probs = (float*)alloc((size_t)Tn * En * 4);
  int* tope = (int*)alloc((size_t)Tn * 2 * 4);
  int* slotmap = (int*)alloc((size_t)Tn * En * 4);
  int* etok = (int*)alloc((size_t)En * CAPn * 4);
  u16* xr_h = (u16*)alloc((size_t)En * CAPn * Dmod * 2);
  u16* xr_l = (u16*)alloc((size_t)En * CAPn * Dmod * 2);
  float* eout = (float*)alloc((size_t)En * CAPn * Dmod * 4);
  u16* hn_h = (u16*)alloc((size_t)Tn * Dmod * 2);
  u16* hn_l = (u16*)alloc((size_t)Tn * Dmod * 2);
  size_t fixed_used = (size_t)(p - (char*)d_ws);

  // per-expert extras: mid pair + w1T pair + w2T pair
  size_t per_e = (size_t)CAPn * DFFn * 2 * 2       // mid hi+lo
               + (size_t)DFFn * Dmod * 2 * 2        // w1T hi+lo
               + (size_t)DFFn * Dmod * 2 * 2;       // w2T hi+lo
  int EG = En;
  while (EG > 1 && fixed_used + (size_t)EG * per_e + 4096 > ws_size) EG >>= 1;
  u16* midh = (u16*)alloc((size_t)EG * CAPn * DFFn * 2);
  u16* midl = (u16*)alloc((size_t)EG * CAPn * DFFn * 2);
  u16* w1th = (u16*)alloc((size_t)EG * DFFn * Dmod * 2);
  u16* w1tl = (u16*)alloc((size_t)EG * DFFn * Dmod * 2);
  u16* w2th = (u16*)alloc((size_t)EG * DFFn * Dmod * 2);
  u16* w2tl = (u16*)alloc((size_t)EG * DFFn * Dmod * 2);
  bool full = (EG == En);

  rope_tables<<<(Tn * DHn + 255) / 256, 256, 0, stream>>>(cosT, sinT);
  embed_gather<<<(Tn * Dmod / 4 + 255) / 256, 256, 0, stream>>>(ids, ew, h);

  if (full) {  // weights resident: transpose+split once per launch
    transpose_split<<<dim3(DFFn / 64, Dmod / 64, En), 256, 0, stream>>>(
        w1, w1th, w1tl, Dmod, DFFn);
    transpose_split<<<dim3(Dmod / 64, DFFn / 64, En), 256, 0, stream>>>(
        w2, w2th, w2tl, DFFn, Dmod);
  }

  float* hin = h;
  float* hout = h2;
  for (int hop = 0; hop < HOPSn; ++hop) {
    router_kernel<<<Tn, 64, 0, stream>>>(hin, rw + (size_t)hop * Dmod * En,
                                         logits, probs, tope, slotmap);
    assign_kernel<<<En, 256, 0, stream>>>(logits, tope, etok, slotmap);
    dispatch_rope<<<En * CAPn, 256, 0, stream>>>(etok, hin, cosT, sinT, xr_h,
                                                 xr_l);
    for (int g = 0; g < En / EG; ++g) {
      if (!full) {
        transpose_split<<<dim3(DFFn / 64, Dmod / 64, EG), 256, 0, stream>>>(
            w1 + (size_t)g * EG * Dmod * DFFn, w1th, w1tl, Dmod, DFFn);
        transpose_split<<<dim3(Dmod / 64, DFFn / 64, EG), 256, 0, stream>>>(
            w2 + (size_t)g * EG * DFFn * Dmod, w2th, w2tl, DFFn, Dmod);
      }
      size_t xoff = (size_t)g * EG * CAPn * Dmod;
      // GEMM1: mid = gelu(xr @ w1)  [512 x 4096], K=1024, split output
      gemm_mfma<false, true, true><<<dim3(DFFn / 128, CAPn / 128, EG), 256, 0,
                                     stream>>>(
          xr_h + xoff, xr_l + xoff, w1th, w1tl, nullptr, nullptr, midh, midl,
          CAPn, DFFn, Dmod, (long)CAPn * Dmod, (long)DFFn * Dmod,
          (long)CAPn * DFFn);
      // GEMM2: eout = mid @ w2  [512 x 1024], K=4096, fp32 output
      gemm_mfma<false, false, false><<<dim3(Dmod / 128, CAPn / 128, EG), 256,
                                       0, stream>>>(
          midh, midl, w2th, w2tl, nullptr, eout + xoff, nullptr, nullptr,
          CAPn, Dmod, DFFn, (long)CAPn * DFFn, (long)Dmod * DFFn,
          (long)CAPn * Dmod);
    }
    combine_kernel<<<Tn, 256, 0, stream>>>(hin, eout, probs, tope, slotmap,
                                           hout);
    float* tmp = hin; hin = hout; hout = tmp;
  }
  rmsnorm_kernel<<<Tn, 256, 0, stream>>>(hin, lns, hn_h, hn_l);
  // Final: logits = hn @ embed^T  [2048 x 32000], K=1024; embed is [V][D]
  // (K-contiguous) so it feeds B directly as fp32, converted during staging.
  gemm_mfma<true, false, false><<<dim3(Vn / 128, Tn / 128, 1), 256, 0,
                                  stream>>>(
      hn_h, hn_l, nullptr, nullptr, ew, out, nullptr, nullptr, Tn, Vn, Dmod,
      0, 0, 0);
}